// Round 11
// baseline (228.725 us; speedup 1.0000x reference)
//
#include <hip/hip_runtime.h>
#include <math.h>

// PeakAreaFloodLoss: B=2048 rows, S=8192 cols, fp32 p/t + i32 mask -> scalar.
// R5 post-mortem: atomics & dispatch-rate theories dead (512-block no-atomic
// variant was WORSE). Invariant across R2/R3/R5: ~2.5 TB/s effective read BW,
// VALU 17%, HBM 15% => latency-bound. Theory: compiler minimized VGPRs
// (36/52/56) and serialized the 6 loads/thread (1-2 in flight). R6..R11:
// hoist all 6 loads into named registers BEFORE any compute; plus an in-situ
// pure-read BW probe kernel to measure the achievable ceiling in-harness.

#define S_LEN 8192
#define BLK   1024
#define NWAVE (BLK / 64)          // 16

__device__ __forceinline__ float waveSum(float x) {
    #pragma unroll
    for (int o = 32; o > 0; o >>= 1) x += __shfl_down(x, o, 64);
    return x;
}
__device__ __forceinline__ float waveMax(float x) {
    #pragma unroll
    for (int o = 32; o > 0; o >>= 1) x = fmaxf(x, __shfl_down(x, o, 64));
    return x;
}

__global__ __launch_bounds__(BLK) void flood_loss_row(
    const float* __restrict__ P, const float* __restrict__ T,
    const int* __restrict__ M, float* __restrict__ partial)
{
    __shared__ float red1[NWAVE][4];
    __shared__ float red2[NWAVE][2];

    const int tid  = threadIdx.x;
    const int wid  = tid >> 6;
    const int lane = tid & 63;
    const size_t base = (size_t)blockIdx.x * S_LEN;

    const float4* __restrict__ P4 = (const float4*)(P + base);
    const float4* __restrict__ T4 = (const float4*)(T + base);
    const int4*   __restrict__ M4 = (const int4*)(M + base);

    // ---- hoisted loads: all 6 x 16B issued before ANY compute ----
    float4 p0 = P4[tid];
    float4 p1 = P4[BLK + tid];
    float4 t0 = T4[tid];
    float4 t1 = T4[BLK + tid];
    int4   m0 = M4[tid];
    int4   m1 = M4[BLK + tid];

    float pe[8] = {p0.x, p0.y, p0.z, p0.w, p1.x, p1.y, p1.z, p1.w};
    float te[8] = {t0.x, t0.y, t0.z, t0.w, t1.x, t1.y, t1.z, t1.w};
    int   me[8] = {m0.x, m0.y, m0.z, m0.w, m1.x, m1.y, m1.z, m1.w};

    // ---- pass 1: stats + register staging ----
    float tenc[8]; // t, invalid -> -INF (one-compare 'high' test)
    float d2v [8]; // valid ? (p-t)^2 : 0
    float ssq = 0.f, fn = 0.f;
    float tpk = -INFINITY, ppk = -INFINITY;

    #pragma unroll
    for (int j = 0; j < 8; ++j) {
        // valid = mask && !isnan(p) && !isnan(t)   (x!=x is the NaN test)
        bool valid = (me[j] != 0) && !(pe[j] != pe[j]) && !(te[j] != te[j]);
        float d  = pe[j] - te[j];
        float d2 = valid ? d * d : 0.f;
        ssq += d2;
        fn  += valid ? 1.f : 0.f;
        if (valid) { tpk = fmaxf(tpk, te[j]); ppk = fmaxf(ppk, pe[j]); }
        tenc[j] = valid ? te[j] : -INFINITY;
        d2v [j] = d2;
    }
    // Pin staged values AFTER all loads consumed (prevents pass-2 re-load
    // rematerialization; R3 proved correctness of this idiom).
    asm volatile("" : "+v"(tenc[0]), "+v"(tenc[1]), "+v"(tenc[2]), "+v"(tenc[3]),
                      "+v"(tenc[4]), "+v"(tenc[5]), "+v"(tenc[6]), "+v"(tenc[7]),
                      "+v"(d2v[0]), "+v"(d2v[1]), "+v"(d2v[2]), "+v"(d2v[3]),
                      "+v"(d2v[4]), "+v"(d2v[5]), "+v"(d2v[6]), "+v"(d2v[7]));

    ssq = waveSum(ssq); fn = waveSum(fn);
    tpk = waveMax(tpk); ppk = waveMax(ppk);
    if (lane == 0) { red1[wid][0] = fn; red1[wid][1] = ssq; red1[wid][2] = tpk; red1[wid][3] = ppk; }
    __syncthreads();

    float fnT = 0.f, ssqT = 0.f, tpkT = -INFINITY, ppkT = -INFINITY;
    #pragma unroll
    for (int w = 0; w < NWAVE; ++w) {         // same-address LDS reads: broadcast
        fnT  += red1[w][0];
        ssqT += red1[w][1];
        tpkT  = fmaxf(tpkT, red1[w][2]);
        ppkT  = fmaxf(ppkT, red1[w][3]);
    }

    // ---- pass 2: high subset, from pinned registers ----
    // ref: high = valid & (t_peak<=0 ? true : t >= 0.8*t_peak)
    const bool  tpos = tpkT > 0.f;
    const float thr  = tpkT * 0.8f;
    float nh = 0.f, ssqh = 0.f;
    #pragma unroll
    for (int k = 0; k < 8; ++k) {
        bool hi = tpos ? (tenc[k] >= thr) : (tenc[k] > -INFINITY);
        nh   += hi ? 1.f : 0.f;
        ssqh += hi ? d2v[k] : 0.f;
    }
    nh = waveSum(nh); ssqh = waveSum(ssqh);
    if (lane == 0) { red2[wid][0] = nh; red2[wid][1] = ssqh; }
    __syncthreads();

    if (tid == 0) {
        float nht = 0.f, ssqht = 0.f;
        #pragma unroll
        for (int w = 0; w < NWAVE; ++w) { nht += red2[w][0]; ssqht += red2[w][1]; }
        float overall = (fnT > 0.f) ? sqrtf(ssqT  / fmaxf(fnT, 1.f)) : 0.f;
        float high_r  = (nht > 0.f) ? sqrtf(ssqht / fmaxf(nht, 1.f)) : 0.f;
        float peak_e  = (fnT > 0.f) ? fabsf(ppkT - tpkT) : 0.f;
        partial[blockIdx.x] = 0.5f * overall + 2.0f * peak_e + 1.0f * high_r;
    }
}

// In-situ HBM read-BW ceiling probe: barrier-free grid-stride pure read of the
// same 201 MB, structured like the known-6.3TB/s copy bench (256 thr, low regs).
// Launched AFTER the main kernel so it cannot warm caches for it.
__global__ __launch_bounds__(256) void bw_probe(
    const float4* __restrict__ P4, const float4* __restrict__ T4,
    const int4* __restrict__ M4, float* __restrict__ sink, int n4)
{
    float acc = 0.f;
    const int stride = gridDim.x * 256;
    for (int i = blockIdx.x * 256 + threadIdx.x; i < n4; i += stride) {
        float4 a = P4[i];
        float4 b = T4[i];
        int4   m = M4[i];
        acc += a.x + a.y + a.z + a.w + b.x + b.y + b.z + b.w
             + (float)(m.x + m.y + m.z + m.w);
    }
    acc = waveSum(acc);
    if ((threadIdx.x & 63) == 0) sink[blockIdx.x * 4 + (threadIdx.x >> 6)] = acc;
}

// 2048 partials -> mean loss. One 1024-thread block.
__global__ __launch_bounds__(1024) void flood_loss_reduce(
    const float* __restrict__ partial, float* __restrict__ out, float invB)
{
    __shared__ float s[16];
    const int tid  = threadIdx.x;
    const int wid  = tid >> 6;
    const int lane = tid & 63;
    float x = partial[tid] + partial[tid + 1024];
    x = waveSum(x);
    if (lane == 0) s[wid] = x;
    __syncthreads();
    if (tid == 0) {
        float tot = 0.f;
        #pragma unroll
        for (int w = 0; w < 16; ++w) tot += s[w];
        out[0] = tot * invB; // overwrite: no memset needed
    }
}

extern "C" void kernel_launch(void* const* d_in, const int* in_sizes, int n_in,
                              void* d_out, int out_size, void* d_ws, size_t ws_size,
                              hipStream_t stream) {
    const float* P = (const float*)d_in[0];
    const float* T = (const float*)d_in[1];
    const int*   M = (const int*)d_in[2];
    float* out = (float*)d_out;
    float* partial = (float*)d_ws;                 // 2048 floats
    float* sink    = (float*)d_ws + 4096;          // 8192 floats (probe)
    const int B = in_sizes[0] / S_LEN;             // 2048
    const int n4 = in_sizes[0] / 4;                // float4 count per array

    flood_loss_row<<<B, BLK, 0, stream>>>(P, T, M, partial);
    flood_loss_reduce<<<1, 1024, 0, stream>>>(partial, out, 1.0f / (float)B);
    if (ws_size >= (4096 + 8192) * sizeof(float)) {
        bw_probe<<<2048, 256, 0, stream>>>((const float4*)P, (const float4*)T,
                                           (const int4*)M, sink, n4);
    }
}

// Round 13
// 205.416 us; speedup vs baseline: 1.1135x; 1.1135x over previous
//
#include <hip/hip_runtime.h>
#include <math.h>

// PeakAreaFloodLoss: B=2048 rows, S=8192 cols, fp32 p/t + i32 mask -> scalar.
// R11 verdict: hoist arm FAILED (VGPR 52 unchanged, dur 74.5us); bw_probe arm
// FAST (~32us / ~6 TB/s inferred from constant ~119us headline overhead).
// => restructure main kernel LIKE THE PROBE: 256-thr blocks, one row/block,
// 24x16B streamed loads per sweep (compiler software-pipelines => deep MLP),
// no mid-stream barriers. Sweep 2 re-reads the row from L3 (192 MB fits in
// 256 MB Infinity Cache) instead of staging -> both sweeps run at stream rate.

#define S_LEN 8192
#define BLK   256
#define NWAVE (BLK / 64)          // 4
#define NIT   (S_LEN / 4 / BLK)   // 8 float4 per thread per array

__device__ __forceinline__ float waveSum(float x) {
    #pragma unroll
    for (int o = 32; o > 0; o >>= 1) x += __shfl_down(x, o, 64);
    return x;
}
__device__ __forceinline__ float waveMax(float x) {
    #pragma unroll
    for (int o = 32; o > 0; o >>= 1) x = fmaxf(x, __shfl_down(x, o, 64));
    return x;
}

__global__ __launch_bounds__(BLK) void flood_loss2(
    const float* __restrict__ P, const float* __restrict__ T,
    const int* __restrict__ M, float* __restrict__ partial)
{
    __shared__ float red1[NWAVE][4];
    __shared__ float red2[NWAVE][2];

    const int tid  = threadIdx.x;
    const int wid  = tid >> 6;
    const int lane = tid & 63;
    const size_t base = (size_t)blockIdx.x * S_LEN;

    const float4* __restrict__ P4 = (const float4*)(P + base);
    const float4* __restrict__ T4 = (const float4*)(T + base);
    const int4*   __restrict__ M4 = (const int4*)(M + base);

    // ---- sweep 1: probe-shaped accumulation stream (no staging) ----
    float ssq = 0.f, fn = 0.f;
    float tpk = -INFINITY, ppk = -INFINITY;

    #pragma unroll
    for (int it = 0; it < NIT; ++it) {
        const int v = it * BLK + tid;      // float4 index, coalesced
        float4 p4 = P4[v];
        float4 t4 = T4[v];
        int4   m4 = M4[v];
        float pe[4] = {p4.x, p4.y, p4.z, p4.w};
        float te[4] = {t4.x, t4.y, t4.z, t4.w};
        int   me[4] = {m4.x, m4.y, m4.z, m4.w};
        #pragma unroll
        for (int j = 0; j < 4; ++j) {
            // valid = mask && !isnan(p) && !isnan(t)  (x!=x is the NaN test)
            bool valid = (me[j] != 0) && !(pe[j] != pe[j]) && !(te[j] != te[j]);
            float d = pe[j] - te[j];
            ssq += valid ? d * d : 0.f;
            fn  += valid ? 1.f : 0.f;
            if (valid) { tpk = fmaxf(tpk, te[j]); ppk = fmaxf(ppk, pe[j]); }
        }
    }

    ssq = waveSum(ssq); fn = waveSum(fn);
    tpk = waveMax(tpk); ppk = waveMax(ppk);
    if (lane == 0) { red1[wid][0] = fn; red1[wid][1] = ssq; red1[wid][2] = tpk; red1[wid][3] = ppk; }
    __syncthreads();

    float fnT = 0.f, ssqT = 0.f, tpkT = -INFINITY, ppkT = -INFINITY;
    #pragma unroll
    for (int w = 0; w < NWAVE; ++w) {      // same-address LDS reads: broadcast
        fnT  += red1[w][0];
        ssqT += red1[w][1];
        tpkT  = fmaxf(tpkT, red1[w][2]);
        ppkT  = fmaxf(ppkT, red1[w][3]);
    }

    // ---- sweep 2: re-read row (L3-resident after sweep 1), high subset ----
    // ref: high = valid & (t_peak<=0 ? true : t >= 0.8*t_peak)
    const bool  tpos = tpkT > 0.f;
    const float thr  = tpkT * 0.8f;
    float nh = 0.f, ssqh = 0.f;

    #pragma unroll
    for (int it = 0; it < NIT; ++it) {
        const int v = it * BLK + tid;
        float4 p4 = P4[v];
        float4 t4 = T4[v];
        int4   m4 = M4[v];
        float pe[4] = {p4.x, p4.y, p4.z, p4.w};
        float te[4] = {t4.x, t4.y, t4.z, t4.w};
        int   me[4] = {m4.x, m4.y, m4.z, m4.w};
        #pragma unroll
        for (int j = 0; j < 4; ++j) {
            bool valid = (me[j] != 0) && !(pe[j] != pe[j]) && !(te[j] != te[j]);
            bool hi = valid && (!tpos || te[j] >= thr);
            float d = pe[j] - te[j];
            nh   += hi ? 1.f : 0.f;
            ssqh += hi ? d * d : 0.f;
        }
    }

    nh = waveSum(nh); ssqh = waveSum(ssqh);
    if (lane == 0) { red2[wid][0] = nh; red2[wid][1] = ssqh; }
    __syncthreads();

    if (tid == 0) {
        float nht = 0.f, ssqht = 0.f;
        #pragma unroll
        for (int w = 0; w < NWAVE; ++w) { nht += red2[w][0]; ssqht += red2[w][1]; }
        float overall = (fnT > 0.f) ? sqrtf(ssqT  / fmaxf(fnT, 1.f)) : 0.f;
        float high_r  = (nht > 0.f) ? sqrtf(ssqht / fmaxf(nht, 1.f)) : 0.f;
        float peak_e  = (fnT > 0.f) ? fabsf(ppkT - tpkT) : 0.f;
        partial[blockIdx.x] = 0.5f * overall + 2.0f * peak_e + 1.0f * high_r;
    }
}

// 2048 partials -> mean loss. One 1024-thread block.
__global__ __launch_bounds__(1024) void flood_loss_reduce(
    const float* __restrict__ partial, float* __restrict__ out, float invB)
{
    __shared__ float s[16];
    const int tid  = threadIdx.x;
    const int wid  = tid >> 6;
    const int lane = tid & 63;
    float x = partial[tid] + partial[tid + 1024];
    x = waveSum(x);
    if (lane == 0) s[wid] = x;
    __syncthreads();
    if (tid == 0) {
        float tot = 0.f;
        #pragma unroll
        for (int w = 0; w < 16; ++w) tot += s[w];
        out[0] = tot * invB; // overwrite: no memset needed
    }
}

extern "C" void kernel_launch(void* const* d_in, const int* in_sizes, int n_in,
                              void* d_out, int out_size, void* d_ws, size_t ws_size,
                              hipStream_t stream) {
    const float* P = (const float*)d_in[0];
    const float* T = (const float*)d_in[1];
    const int*   M = (const int*)d_in[2];
    float* out = (float*)d_out;
    float* partial = (float*)d_ws;       // 2048 floats, fully overwritten
    const int B = in_sizes[0] / S_LEN;   // 2048

    flood_loss2<<<B, BLK, 0, stream>>>(P, T, M, partial);
    flood_loss_reduce<<<1, 1024, 0, stream>>>(partial, out, 1.0f / (float)B);
}